// Round 6
// baseline (630.269 us; speedup 1.0000x reference)
//
#include <hip/hip_runtime.h>
#include <math.h>

#define NCH 192
#define NB 8
#define SPAT 32768                        // 32^3
#define TILES_ALL 512                     // 64-pos tiles per sample
#define NELEM_PER_B ((size_t)NCH * SPAT)  // 6291456

typedef short s16x8 __attribute__((ext_vector_type(8)));
typedef float f32x4 __attribute__((ext_vector_type(4)));

__device__ __forceinline__ float bf2f(unsigned short h) {
  return __uint_as_float(((unsigned)h) << 16);
}
__device__ __forceinline__ unsigned short f2bf(float f) {
  unsigned u = __float_as_uint(f);
  u += 0x7FFF + ((u >> 16) & 1);   // round-to-nearest-even
  return (unsigned short)(u >> 16);
}

// erf via Abramowitz-Stegun 7.1.26, |abs err| < 1.5e-7
__device__ __forceinline__ float erf_fast(float x) {
  float ax = fabsf(x);
  float t = 1.0f / fmaf(0.3275911f, ax, 1.0f);
  float p = t * fmaf(t, fmaf(t, fmaf(t, fmaf(t, 1.061405429f, -1.453152027f),
                                     1.421413741f), -0.284496736f), 0.254829592f);
  float r = 1.0f - p * __expf(-ax * ax);
  return copysignf(r, x);
}
__device__ __forceinline__ float gelu_exact(float x) {
  return 0.5f * x * (1.0f + erf_fast(x * 0.70710678118654752f));
}

// reflect-shift source position: out[i] = x[i-s], reflect(-1)->1, reflect(32)->30
template <int AX>  // 0 none, 2=D, 3=H, 4=W
__device__ __forceinline__ int shift_src(int p, int s) {
  if (AX == 0) return p;
  const int SH = (AX == 4) ? 0 : (AX == 3) ? 5 : 10;
  int i = (p >> SH) & 31;
  int j = i - s;
  j = (j < 0) ? 1 : j;
  j = (j > 31) ? 30 : j;
  return p + ((j - i) << SH);
}

// LDS tile: [chunk c:3][pos p:64][ch-in-chunk u:64] bf16 (128B rows).
// 16B-granule swizzle g7 = (u>>3)^(p&7)^(p>>3): every access pattern in this
// file (b128 col reads, uint2/b32 epi+transpose writes, s16x8 coop r/w) is
// <=2-way (free).  SINGLE helper for all LDS accesses (rule #21).
__device__ __forceinline__ int lds_off(int c, int p, int u) {
  return (c * 64 + p) * 128 + 16 * (((u >> 3) ^ (p & 7) ^ (p >> 3)) & 7) + 2 * (u & 7);
}

// Raw workgroup barriers (T3/T4): NEVER drain vmcnt inside the tile loop —
// prefetch loads must stay in flight across barriers.  lgkm variant makes
// issued ds_writes visible.  sched_barrier(0) + memory clobber pin both sides.
__device__ __forceinline__ void bar_lgkm() {
  __builtin_amdgcn_sched_barrier(0);
  asm volatile("s_waitcnt lgkmcnt(0)" ::: "memory");
  __builtin_amdgcn_s_barrier();
  asm volatile("" ::: "memory");
  __builtin_amdgcn_sched_barrier(0);
}
__device__ __forceinline__ void bar_plain() {
  __builtin_amdgcn_sched_barrier(0);
  asm volatile("" ::: "memory");
  __builtin_amdgcn_s_barrier();
  asm volatile("" ::: "memory");
  __builtin_amdgcn_sched_barrier(0);
}

// Weight A-fragments for one 192x48 wave-slice (18 x 16B, L2-resident).
__device__ __forceinline__ void load_af(const unsigned short* __restrict__ wb,
                                        int wave, int col, int kg, s16x8 af[6][3]) {
#pragma unroll
  for (int ks = 0; ks < 6; ++ks)
#pragma unroll
    for (int r = 0; r < 3; ++r)
      af[ks][r] = *(const s16x8*)(wb + (wave * 48 + r * 16 + col) * NCH + ks * 32 + kg * 8);
}

// One 192x64 GEMM accumulate from preloaded A-fragments + LDS B-tile.
template <int SHIFTW>
__device__ __forceinline__ void do_gemm(const char* __restrict__ W,
                                        const s16x8 af[6][3],
                                        int col, int kg, f32x4 acc[3][4]) {
#pragma unroll
  for (int ks = 0; ks < 6; ++ks) {
    int k0 = ks * 32 + kg * 8;
    int c = k0 >> 6, u = k0 & 63;
    s16x8 bf[4];
#pragma unroll
    for (int m = 0; m < 4; ++m) {
      int p = m * 16 + col;
      int ps = SHIFTW ? shift_src<4>(p, c - 1) : p;
      bf[m] = *(const s16x8*)(W + lds_off(c, ps, u));
    }
#pragma unroll
    for (int r = 0; r < 3; ++r)
#pragma unroll
      for (int m = 0; m < 4; ++m)
        acc[r][m] = __builtin_amdgcn_mfma_f32_16x16x32_bf16(af[ks][r], bf[m], acc[r][m], 0, 0, 0);
  }
}

// ---------------------------------------------------------------------------
// Pipelined pass.  Per tile: stage(regs->LDS) | issue next-tile loads |
// bar_lgkm | GEMM(s) | bar_plain | epilogue->LDS | bar_lgkm | coop store.
// No vmcnt drain in the loop: next-tile loads overlap the whole compute+store.
//   AX/EPI/OUTF/INF/PERB/FUSE as before; TPWk tiles/WG; CHAIN = K2b+K2c fused
//   (GEMM1 -> in-place T in same LDS buffer -> W-shift -> GEMM2).
// ---------------------------------------------------------------------------
template <int AX, int EPI, int OUTF, int INF, int PERB, int FUSE, int TPWk, int CHAIN>
__global__ __attribute__((amdgpu_flat_work_group_size(256, 256), amdgpu_waves_per_eu(2, 2)))
void gemm_pass(const void* __restrict__ inv,
               const unsigned short* __restrict__ wmat,
               const float* __restrict__ bias,
               const unsigned short* __restrict__ wmat2,
               const float* __restrict__ bias2,
               void* __restrict__ outv,
               float* __restrict__ partials,
               const float* __restrict__ AC) {
  __shared__ __align__(16) char ldsW[2][3 * 64 * 128];   // 48 KB double buffer
  __shared__ float acs[2 * NCH];
  __shared__ float red[4][2];

  constexpr int WGS_PER_B = TILES_ALL / TPWk;
  int wg = blockIdx.x;
  int b = wg / WGS_PER_B;
  int ti0 = (wg % WGS_PER_B) * TPWk;
  int tid = threadIdx.x;
  int wave = tid >> 6;
  int lane = tid & 63;
  int col = lane & 15;
  int kg = lane >> 4;

  const unsigned short* wbase = wmat + (PERB ? (size_t)b * NCH * NCH : 0);
  const float* bbase = bias + (PERB ? b * NCH : 0);
  const char* inbytes = (const char*)inv;
  const float* xin = (const float*)inv;
  float* outf = (float*)outv;

  if (FUSE)
    for (int i = tid; i < 2 * NCH; i += 256) acs[i] = AC[b * 2 * NCH + i];

  // Non-chain: weights held in registers for the whole WG (issued FIRST so
  // their vmcnt wait never drains the staging prefetch behind them).
  s16x8 afH[6][3];
  if (!CHAIN) load_af(wbase, wave, col, kg, afH);

  // ---- prologue loads: tile ti0 -> staging registers ----
  s16x8 vr[6];          // INF==0
  f32x4 xa[6], xb[6];   // INF==1 (paired channels 2cp, 2cp+1)
  {
    int P0 = ti0 * 64;
    if (INF == 1) {
#pragma unroll
      for (int j = 0; j < 6; ++j) {
        int q = j * 256 + tid, cp = q >> 4, g = q & 15;
        const float* bp = xin + (size_t)b * NELEM_PER_B + (size_t)(2 * cp) * SPAT + P0 + 4 * g;
        xa[j] = *(const f32x4*)bp;
        xb[j] = *(const f32x4*)(bp + SPAT);
      }
    } else {
#pragma unroll
      for (int j = 0; j < 6; ++j) {
        unsigned g = j * 256 + tid;
        int p = (int)(g / 24u), r24 = (int)(g - 24u * (unsigned)p);
        int ps = shift_src<AX>(P0 + p, (r24 >> 3) - 1);
        vr[j] = *(const s16x8*)(inbytes + ((size_t)b * SPAT + ps) * 384 + r24 * 16);
      }
    }
  }
  if (FUSE) __syncthreads();   // acs visible (prologue; drain harmless)

  float ssum = 0.f, ssq = 0.f;

  for (int t = 0; t < TPWk; ++t) {
    char* W = ldsW[t & 1];
    int p0 = (ti0 + t) * 64;

    // ---- stage tile t: regs -> W ----
    if (INF == 1) {
#pragma unroll
      for (int j = 0; j < 6; ++j) {
        int q = j * 256 + tid, cp = q >> 4, g = q & 15;
        int c = (2 * cp) >> 6, u0 = (2 * cp) & 63;
#pragma unroll
        for (int i = 0; i < 4; ++i) {
          unsigned pk = (unsigned)f2bf(xa[j][i]) | ((unsigned)f2bf(xb[j][i]) << 16);
          *(unsigned*)(W + lds_off(c, 4 * g + i, u0)) = pk;
        }
      }
    } else {
#pragma unroll
      for (int j = 0; j < 6; ++j) {
        unsigned g = j * 256 + tid;
        int p = (int)(g / 24u), r24 = (int)(g - 24u * (unsigned)p);
        s16x8 v = vr[j];
        if (FUSE) {
          int ch0 = r24 * 8;
#pragma unroll
          for (int u = 0; u < 8; ++u) {
            float f = bf2f((unsigned short)v[u]);
            f = fmaf(f, acs[ch0 + u], acs[NCH + ch0 + u]);
            f = gelu_exact(f);
            v[u] = (short)f2bf(f);
          }
        }
        *(s16x8*)(W + lds_off(r24 >> 3, p, (r24 & 7) * 8)) = v;
      }
    }

    // CHAIN: per-tile GEMM1 weights, issued BEFORE the prefetch.
    s16x8 af1[6][3];
    if (CHAIN) load_af(wbase, wave, col, kg, af1);

    // ---- issue next tile's loads (stay in flight across compute+store) ----
    if (t + 1 < TPWk) {
      int p1 = (ti0 + t + 1) * 64;
      if (INF == 1) {
#pragma unroll
        for (int j = 0; j < 6; ++j) {
          int q = j * 256 + tid, cp = q >> 4, g = q & 15;
          const float* bp = xin + (size_t)b * NELEM_PER_B + (size_t)(2 * cp) * SPAT + p1 + 4 * g;
          xa[j] = *(const f32x4*)bp;
          xb[j] = *(const f32x4*)(bp + SPAT);
        }
      } else {
#pragma unroll
        for (int j = 0; j < 6; ++j) {
          unsigned g = j * 256 + tid;
          int p = (int)(g / 24u), r24 = (int)(g - 24u * (unsigned)p);
          int ps = shift_src<AX>(p1 + p, (r24 >> 3) - 1);
          vr[j] = *(const s16x8*)(inbytes + ((size_t)b * SPAT + ps) * 384 + r24 * 16);
        }
      }
    }

    bar_lgkm();   // B1: staged tile visible; prefetch NOT drained

    f32x4 acc[3][4] = {};
    if constexpr (CHAIN) {
      do_gemm<0>(W, af1, col, kg, acc);
      bar_plain();   // B2: all GEMM1 reads of W retired
      // epi1: +bias -> T, in place in W
#pragma unroll
      for (int r = 0; r < 3; ++r) {
        int rowb = wave * 48 + r * 16 + kg * 4;
        f32x4 bs = *(const f32x4*)(bbase + rowb);
#pragma unroll
        for (int m = 0; m < 4; ++m) {
          int p = m * 16 + col;
          uint2 pk;
          pk.x = (unsigned)f2bf(acc[r][m][0] + bs[0]) | ((unsigned)f2bf(acc[r][m][1] + bs[1]) << 16);
          pk.y = (unsigned)f2bf(acc[r][m][2] + bs[2]) | ((unsigned)f2bf(acc[r][m][3] + bs[3]) << 16);
          *(uint2*)(W + lds_off(rowb >> 6, p, rowb & 63)) = pk;
        }
      }
      s16x8 af2[6][3];
      load_af(wmat2, wave, col, kg, af2);   // af2 wait may drain prefetch, but
                                            // prefetch has had ~GEMM1 to land
      bar_lgkm();    // B3: T visible
#pragma unroll
      for (int r = 0; r < 3; ++r)
#pragma unroll
        for (int m = 0; m < 4; ++m) acc[r][m] = (f32x4){0.f, 0.f, 0.f, 0.f};
      do_gemm<1>(W, af2, col, kg, acc);     // W-axis shift at read
      bar_plain();   // B4: GEMM2 reads retired
      // epi2: bias2 (+gelu+stats) -> W
#pragma unroll
      for (int r = 0; r < 3; ++r) {
        int rowb = wave * 48 + r * 16 + kg * 4;
        f32x4 bs = *(const f32x4*)(bias2 + rowb);
#pragma unroll
        for (int m = 0; m < 4; ++m) {
          int p = m * 16 + col;
          float v[4];
#pragma unroll
          for (int j = 0; j < 4; ++j) {
            float tv = acc[r][m][j] + bs[j];
            if (EPI == 2) tv = gelu_exact(tv);
            if (EPI >= 1) { ssum += tv; ssq = fmaf(tv, tv, ssq); }
            v[j] = tv;
          }
          uint2 pk;
          pk.x = (unsigned)f2bf(v[0]) | ((unsigned)f2bf(v[1]) << 16);
          pk.y = (unsigned)f2bf(v[2]) | ((unsigned)f2bf(v[3]) << 16);
          *(uint2*)(W + lds_off(rowb >> 6, p, rowb & 63)) = pk;
        }
      }
      bar_lgkm();    // B5: output tile visible
      char* outbytes = (char*)outv + ((size_t)b * SPAT + p0) * 384;
#pragma unroll
      for (int j = 0; j < 6; ++j) {
        unsigned g = j * 256 + tid;
        int p = (int)(g / 24u), r24 = (int)(g - 24u * (unsigned)p);
        s16x8 v = *(const s16x8*)(W + lds_off(r24 >> 3, p, (r24 & 7) * 8));
        *(s16x8*)(outbytes + g * 16) = v;
      }
    } else {
      do_gemm<0>(W, afH, col, kg, acc);
      if (OUTF == 0) bar_plain();   // B2: reads retired, W reusable as out tile
#pragma unroll
      for (int r = 0; r < 3; ++r) {
        int rowb = wave * 48 + r * 16 + kg * 4;
        f32x4 bs = *(const f32x4*)(bbase + rowb);
#pragma unroll
        for (int m = 0; m < 4; ++m) {
          int p = m * 16 + col;
          float v[4];
#pragma unroll
          for (int j = 0; j < 4; ++j) {
            float tv = acc[r][m][j] + bs[j];
            if (EPI == 2) tv = gelu_exact(tv);
            if (EPI >= 1) { ssum += tv; ssq = fmaf(tv, tv, ssq); }
            v[j] = tv;
          }
          if (OUTF == 0) {
            uint2 pk;
            pk.x = (unsigned)f2bf(v[0]) | ((unsigned)f2bf(v[1]) << 16);
            pk.y = (unsigned)f2bf(v[2]) | ((unsigned)f2bf(v[3]) << 16);
            *(uint2*)(W + lds_off(rowb >> 6, p, rowb & 63)) = pk;
          } else {
#pragma unroll
            for (int j = 0; j < 4; ++j)
              outf[((size_t)b * NCH + rowb + j) * SPAT + p0 + p] = v[j];
          }
        }
      }
      if (OUTF == 0) {
        bar_lgkm();   // B3: out tile visible
        char* outbytes = (char*)outv + ((size_t)b * SPAT + p0) * 384;
#pragma unroll
        for (int j = 0; j < 6; ++j) {
          unsigned g = j * 256 + tid;
          int p = (int)(g / 24u), r24 = (int)(g - 24u * (unsigned)p);
          s16x8 v = *(const s16x8*)(W + lds_off(r24 >> 3, p, (r24 & 7) * 8));
          *(s16x8*)(outbytes + g * 16) = v;
        }
      }
    }
  }

  if (EPI >= 1) {
#pragma unroll
    for (int off = 1; off < 64; off <<= 1) {
      ssum += __shfl_xor(ssum, off, 64);
      ssq += __shfl_xor(ssq, off, 64);
    }
    if (lane == 0) { red[wave][0] = ssum; red[wave][1] = ssq; }
    __syncthreads();
    if (tid == 0) {
      partials[wg * 2]     = red[0][0] + red[1][0] + red[2][0] + red[3][0];
      partials[wg * 2 + 1] = red[0][1] + red[1][1] + red[2][1] + red[3][1];
    }
  }
}

// Deterministic per-sample stats finalize: nper partials per sample
__global__ void stats_finalize(const float* __restrict__ partials,
                               const float* __restrict__ nw,
                               const float* __restrict__ nb,
                               float* __restrict__ AC, int nper) {
  int b = blockIdx.x;
  int tid = threadIdx.x;
  __shared__ float s0[256], s1[256];
  float a = 0.f, c = 0.f;
  for (int i = tid; i < nper; i += 256) {
    a += partials[(b * nper + i) * 2];
    c += partials[(b * nper + i) * 2 + 1];
  }
  s0[tid] = a; s1[tid] = c;
  __syncthreads();
  for (int st = 128; st > 0; st >>= 1) {
    if (tid < st) { s0[tid] += s0[tid + st]; s1[tid] += s1[tid + st]; }
    __syncthreads();
  }
  float inv_n = 1.0f / (float)(NELEM_PER_B);
  float mu = s0[0] * inv_n;
  float var = s1[0] * inv_n - mu * mu;
  float rs = rsqrtf(var + 1e-5f);
  if (tid < NCH) {
    float A = rs * nw[tid];
    AC[b * 2 * NCH + tid] = A;
    AC[b * 2 * NCH + NCH + tid] = nb[tid] - mu * A;
  }
}

// fp32 -> bf16 weight conversion: slots 0=w1, 1=w22, 2=w21, 3=w23
__global__ void prep_weights(const float* __restrict__ w1, const float* __restrict__ w21,
                             const float* __restrict__ w22, const float* __restrict__ w23,
                             unsigned short* __restrict__ wb) {
  int i = blockIdx.x * 256 + threadIdx.x;
  if (i >= 4 * NCH * NCH) return;
  int m = i / (NCH * NCH), r = i % (NCH * NCH);
  const float* src = (m == 0) ? w1 : (m == 1) ? w22 : (m == 2) ? w21 : w23;
  wb[i] = f2bf(src[r]);
}

// Fold norm2 affine into w3/b3 per sample
__global__ void prep_w3(const float* __restrict__ w3, const float* __restrict__ b3,
                        const float* __restrict__ AC2,
                        unsigned short* __restrict__ w3e, float* __restrict__ b3e) {
  int b = blockIdx.x;
  int o = threadIdx.x;
  if (o >= NCH) return;
  const float* A = AC2 + b * 2 * NCH;
  const float* C = A + NCH;
  float s = b3[o];
  for (int c = 0; c < NCH; ++c) {
    float w = w3[o * NCH + c];
    w3e[((size_t)b * NCH + o) * NCH + c] = f2bf(w * A[c]);
    s = fmaf(w, C[c], s);
  }
  b3e[b * NCH + o] = s;
}

extern "C" void kernel_launch(void* const* d_in, const int* in_sizes, int n_in,
                              void* d_out, int out_size, void* d_ws, size_t ws_size,
                              hipStream_t stream) {
  const float* x   = (const float*)d_in[0];
  const float* w1  = (const float*)d_in[1];
  const float* b1  = (const float*)d_in[2];
  const float* n1w = (const float*)d_in[3];
  const float* n1b = (const float*)d_in[4];
  const float* w21 = (const float*)d_in[5];
  const float* b21 = (const float*)d_in[6];
  const float* w22 = (const float*)d_in[7];
  const float* b22 = (const float*)d_in[8];
  const float* w23 = (const float*)d_in[9];
  const float* b23 = (const float*)d_in[10];
  const float* n2w = (const float*)d_in[11];
  const float* n2b = (const float*)d_in[12];
  const float* w3  = (const float*)d_in[13];
  const float* b3  = (const float*)d_in[14];

  char* ws = (char*)d_ws;
  size_t off = 0;
  unsigned short* wb = (unsigned short*)(ws + off); off += (size_t)4 * NCH * NCH * 2;
  off = (off + 255) & ~(size_t)255;
  unsigned short* w3e = (unsigned short*)(ws + off); off += (size_t)NB * NCH * NCH * 2;
  off = (off + 255) & ~(size_t)255;
  float* b3e = (float*)(ws + off); off += NB * NCH * 4;
  float* AC1 = (float*)(ws + off); off += NB * 2 * NCH * 4;
  float* AC2 = (float*)(ws + off); off += NB * 2 * NCH * 4;
  float* part1 = (float*)(ws + off); off += 1024 * 2 * 4;
  float* part2 = (float*)(ws + off); off += 512 * 2 * 4;
  off = (off + 255) & ~(size_t)255;
  unsigned short* R1 = (unsigned short*)(ws + off);   // 100.7 MB bf16 scratch (ws)
  unsigned short* R2 = (unsigned short*)d_out;        // bf16 scratch in d_out space

  prep_weights<<<(4 * NCH * NCH + 255) / 256, 256, 0, stream>>>(w1, w21, w22, w23, wb);

  // K1: x (f32 cmajor) -> R1, W=w1, stats1.  TPW=4 pipelined transpose.
  gemm_pass<0, 1, 0, 1, 0, 0, 4, 0><<<NB * 128, 256, 0, stream>>>(
      x, wb + 0 * NCH * NCH, b1, nullptr, nullptr, R1, part1, nullptr);
  stats_finalize<<<NB, 256, 0, stream>>>(part1, n1w, n1b, AC1, 128);

  // K2a: fused norm1+gelu staging, shift H(3), W=w22: R1 -> R2.  TPW=8.
  gemm_pass<3, 0, 0, 0, 0, 1, 8, 0><<<512, 256, 0, stream>>>(
      R1, wb + 1 * NCH * NCH, b22, nullptr, nullptr, R2, nullptr, AC1);

  // K2bc: shift D(2) stage, GEMM(w21) -> in-place T -> shiftW -> GEMM(w23),
  // gelu+stats2: R2 -> R1.  TPW=8.
  gemm_pass<2, 2, 0, 0, 0, 0, 8, 1><<<512, 256, 0, stream>>>(
      R2, wb + 2 * NCH * NCH, b21, wb + 3 * NCH * NCH, b23, R1, part2, nullptr);
  stats_finalize<<<NB, 256, 0, stream>>>(part2, n2w, n2b, AC2, 64);
  prep_w3<<<NB, NCH, 0, stream>>>(w3, b3, AC2, w3e, b3e);

  // K3: folded norm2 + conv3, f32 channel-major out: R1 -> d_out.  TPW=8.
  gemm_pass<0, 0, 1, 0, 1, 0, 8, 0><<<512, 256, 0, stream>>>(
      R1, w3e, b3e, nullptr, nullptr, d_out, nullptr, nullptr);
}

// Round 7
// 517.290 us; speedup vs baseline: 1.2184x; 1.2184x over previous
//
#include <hip/hip_runtime.h>
#include <math.h>

#define NCH 192
#define NB 8
#define SPAT 32768                        // 32^3
#define TILES_ALL 512                     // 64-pos tiles per sample
#define NELEM_PER_B ((size_t)NCH * SPAT)  // 6291456

typedef short s16x8 __attribute__((ext_vector_type(8)));
typedef float f32x4 __attribute__((ext_vector_type(4)));

__device__ __forceinline__ float bf2f(unsigned short h) {
  return __uint_as_float(((unsigned)h) << 16);
}
__device__ __forceinline__ unsigned short f2bf(float f) {
  unsigned u = __float_as_uint(f);
  u += 0x7FFF + ((u >> 16) & 1);   // round-to-nearest-even
  return (unsigned short)(u >> 16);
}

// erf via Abramowitz-Stegun 7.1.26, |abs err| < 1.5e-7
__device__ __forceinline__ float erf_fast(float x) {
  float ax = fabsf(x);
  float t = 1.0f / fmaf(0.3275911f, ax, 1.0f);
  float p = t * fmaf(t, fmaf(t, fmaf(t, fmaf(t, 1.061405429f, -1.453152027f),
                                     1.421413741f), -0.284496736f), 0.254829592f);
  float r = 1.0f - p * __expf(-ax * ax);
  return copysignf(r, x);
}
__device__ __forceinline__ float gelu_exact(float x) {
  return 0.5f * x * (1.0f + erf_fast(x * 0.70710678118654752f));
}

// reflect-shift source position: out[i] = x[i-s], reflect(-1)->1, reflect(32)->30
template <int AX>  // 0 none, 2=D, 3=H, 4=W
__device__ __forceinline__ int shift_src(int p, int s) {
  if (AX == 0) return p;
  const int SH = (AX == 4) ? 0 : (AX == 3) ? 5 : 10;
  int i = (p >> SH) & 31;
  int j = i - s;
  j = (j < 0) ? 1 : j;
  j = (j > 31) ? 30 : j;
  return p + ((j - i) << SH);
}

// LDS tile: [chunk c:3][pos p:64][ch-in-chunk u:64] bf16 (128B rows).
// 16B-granule XOR swizzle: granule' = (u>>3) ^ (p&7) ^ ((p>>3)&7).
// SINGLE helper for all ds_read/ds_write accesses (rule #21); gload_lds
// staging writes LINEARLY and applies the same XOR on the GLOBAL src addr.
__device__ __forceinline__ int lds_off(int c, int p, int u) {
  return (c * 64 + p) * 128 + 16 * (((u >> 3) ^ (p & 7) ^ (p >> 3)) & 7) + 2 * (u & 7);
}

__device__ __forceinline__ void bar_lgkm() {
  __builtin_amdgcn_sched_barrier(0);
  asm volatile("s_waitcnt lgkmcnt(0)" ::: "memory");
  __builtin_amdgcn_s_barrier();
  asm volatile("" ::: "memory");
  __builtin_amdgcn_sched_barrier(0);
}
__device__ __forceinline__ void bar_plain() {
  __builtin_amdgcn_sched_barrier(0);
  asm volatile("" ::: "memory");
  __builtin_amdgcn_s_barrier();
  asm volatile("" ::: "memory");
  __builtin_amdgcn_sched_barrier(0);
}
__device__ __forceinline__ void wait_vmcnt(int k) {
  __builtin_amdgcn_sched_barrier(0);
  asm volatile("s_waitcnt vmcnt(%0)" :: "i"(k) : "memory");
  __builtin_amdgcn_sched_barrier(0);
}

// Async stage one 24KB tile (64 pos x 192 ch bf16) via global_load_lds.
// LDS dest is linear (wave-uniform base + lane*16); the tile's XOR granule
// swizzle is applied to the global SOURCE address (involution), so swizzled
// ds_reads through lds_off see the right data.  6 wave-instructions per wave.
template <int AX>
__device__ __forceinline__ void stage_gload(const char* __restrict__ inb, size_t brow,
                                            char* Wbuf, int p0, int wv, int lane) {
#pragma unroll
  for (int j = 0; j < 6; ++j) {
    int gl = (j * 4 + wv) * 64 + lane;
    int r = gl >> 3, G = gl & 7;
    int c = r >> 6, p = r & 63;
    int gsw = G ^ (p & 7) ^ ((p >> 3) & 7);
    int ps = shift_src<AX>(p0 + p, c - 1);
    const char* src = inb + (brow + (size_t)ps) * 384 + (c * 8 + gsw) * 16;
    char* dst = Wbuf + (j * 4 + wv) * 1024;
    __builtin_amdgcn_global_load_lds((const __attribute__((address_space(1))) void*)src,
                                     (__attribute__((address_space(3))) void*)dst, 16, 0, 0);
  }
}

// One 192x64 GEMM accumulate: A = weights per-k-step from global (L1/L2-
// resident), B = LDS tile.  SHIFTW applies W-axis reflect-shift at read.
template <int SHIFTW>
__device__ __forceinline__ void do_gemm(const char* __restrict__ W,
                                        const unsigned short* __restrict__ wb,
                                        int wave, int col, int kg, f32x4 acc[3][4]) {
#pragma unroll
  for (int ks = 0; ks < 6; ++ks) {
    int k0 = ks * 32 + kg * 8;
    s16x8 af[3];
#pragma unroll
    for (int r = 0; r < 3; ++r)
      af[r] = *(const s16x8*)(wb + (wave * 48 + r * 16 + col) * NCH + k0);
    int c = k0 >> 6, u = k0 & 63;
    s16x8 bf[4];
#pragma unroll
    for (int m = 0; m < 4; ++m) {
      int p = m * 16 + col;
      int ps = SHIFTW ? shift_src<4>(p, c - 1) : p;
      bf[m] = *(const s16x8*)(W + lds_off(c, ps, u));
    }
#pragma unroll
    for (int r = 0; r < 3; ++r)
#pragma unroll
      for (int m = 0; m < 4; ++m)
        acc[r][m] = __builtin_amdgcn_mfma_f32_16x16x32_bf16(af[r], bf[m], acc[r][m], 0, 0, 0);
  }
}

// ---------------------------------------------------------------------------
// simple_pass: R3-exact structure (TPW=1, __syncthreads), <=64 VGPR, no spill.
//   INF=1: fp32 channel-major transpose-gather staging (K1)
//   INF=0: bf16 [p][c] coalesced chunk gather, optional FUSE norm1+gelu (K2a)
// ---------------------------------------------------------------------------
template <int AX, int EPI, int INF, int FUSE>
__global__ __launch_bounds__(256, 4)
void simple_pass(const void* __restrict__ inv,
                 const unsigned short* __restrict__ wmat,
                 const float* __restrict__ bias,
                 void* __restrict__ outv,
                 float* __restrict__ partials,
                 const float* __restrict__ AC) {
  __shared__ __align__(16) char lds[3 * 64 * 128];   // 24 KB
  __shared__ float acs[2 * NCH];
  __shared__ float red[4][2];

  int wg = blockIdx.x;
  int b = wg / TILES_ALL;
  int p0 = (wg % TILES_ALL) * 64;
  int tid = threadIdx.x;
  int wave = tid >> 6;
  int lane = tid & 63;
  int col = lane & 15;
  int kg = lane >> 4;

  const char* inbytes = (const char*)inv;
  const float* xin = (const float*)inv;

  if (FUSE) {
    for (int i = tid; i < 2 * NCH; i += 256) acs[i] = AC[b * 2 * NCH + i];
    __syncthreads();
  }

  if (INF == 1) {
    int c3 = tid >> 6, p = tid & 63;
    if (c3 < 3) {
      const float* src = xin + (size_t)b * NELEM_PER_B + (size_t)(c3 * 64) * SPAT + p0 + p;
#pragma unroll
      for (int j = 0; j < 8; ++j) {
        s16x8 v;
#pragma unroll
        for (int u = 0; u < 8; ++u)
          v[u] = (short)f2bf(src[(size_t)(8 * j + u) * SPAT]);
        *(s16x8*)(lds + lds_off(c3, p, 8 * j)) = v;
      }
    }
  } else {
#pragma unroll
    for (int j = 0; j < 6; ++j) {
      unsigned g = j * 256 + tid;
      int p = (int)(g / 24u), r24 = (int)(g - 24u * (unsigned)p);
      int ps = shift_src<AX>(p0 + p, (r24 >> 3) - 1);
      s16x8 v = *(const s16x8*)(inbytes + ((size_t)b * SPAT + ps) * 384 + r24 * 16);
      if (FUSE) {
        int ch0 = r24 * 8;
#pragma unroll
        for (int u = 0; u < 8; ++u) {
          float f = bf2f((unsigned short)v[u]);
          f = fmaf(f, acs[ch0 + u], acs[NCH + ch0 + u]);
          f = gelu_exact(f);
          v[u] = (short)f2bf(f);
        }
      }
      *(s16x8*)(lds + lds_off(r24 >> 3, p, (r24 & 7) * 8)) = v;
    }
  }
  __syncthreads();

  f32x4 acc[3][4] = {};
  do_gemm<0>(lds, wmat, wave, col, kg, acc);

  float ssum = 0.f, ssq = 0.f;
  __syncthreads();   // LDS reads done; reuse as output tile
#pragma unroll
  for (int r = 0; r < 3; ++r) {
    int rowb = wave * 48 + r * 16 + kg * 4;
    f32x4 bs = *(const f32x4*)(bias + rowb);
#pragma unroll
    for (int m = 0; m < 4; ++m) {
      int p = m * 16 + col;
      float v[4];
#pragma unroll
      for (int j = 0; j < 4; ++j) {
        float tv = acc[r][m][j] + bs[j];
        if (EPI >= 1) { ssum += tv; ssq = fmaf(tv, tv, ssq); }
        v[j] = tv;
      }
      uint2 pk;
      pk.x = (unsigned)f2bf(v[0]) | ((unsigned)f2bf(v[1]) << 16);
      pk.y = (unsigned)f2bf(v[2]) | ((unsigned)f2bf(v[3]) << 16);
      *(uint2*)(lds + lds_off(rowb >> 6, p, rowb & 63)) = pk;
    }
  }
  __syncthreads();
  char* outbytes = (char*)outv + ((size_t)b * SPAT + p0) * 384;
#pragma unroll
  for (int j = 0; j < 6; ++j) {
    unsigned g = j * 256 + tid;
    int p = (int)(g / 24u), r24 = (int)(g - 24u * (unsigned)p);
    s16x8 v = *(const s16x8*)(lds + lds_off(r24 >> 3, p, (r24 & 7) * 8));
    *(s16x8*)(outbytes + g * 16) = v;
  }

  if (EPI >= 1) {
#pragma unroll
    for (int off = 1; off < 64; off <<= 1) {
      ssum += __shfl_xor(ssum, off, 64);
      ssq += __shfl_xor(ssq, off, 64);
    }
    if (lane == 0) { red[wave][0] = ssum; red[wave][1] = ssq; }
    __syncthreads();
    if (tid == 0) {
      partials[wg * 2]     = red[0][0] + red[1][0] + red[2][0] + red[3][0];
      partials[wg * 2 + 1] = red[0][1] + red[1][1] + red[2][1] + red[3][1];
    }
  }
}

// ---------------------------------------------------------------------------
// k2bc_pass: gload-staged CHAIN (shiftD stage -> w21 -> in-LDS T -> shiftW
// read -> w23 + gelu + stats).  TPW=4, dbuf, counted vmcnt.  <=128 VGPR.
// ---------------------------------------------------------------------------
#define TPW 4
__global__ __launch_bounds__(256, 3)
void k2bc_pass(const void* __restrict__ inv,
               const unsigned short* __restrict__ w21b,
               const float* __restrict__ b21,
               const unsigned short* __restrict__ w23b,
               const float* __restrict__ b23,
               void* __restrict__ outv,
               float* __restrict__ partials) {
  __shared__ __align__(16) char buf[2][3 * 64 * 128];   // 2 x 24 KB
  __shared__ float red[4][2];

  int wg = blockIdx.x;
  int b = wg / (TILES_ALL / TPW);
  int ti0 = (wg % (TILES_ALL / TPW)) * TPW;
  int tid = threadIdx.x;
  int wave = tid >> 6;
  int lane = tid & 63;
  int col = lane & 15;
  int kg = lane >> 4;

  const char* inbytes = (const char*)inv;
  size_t brow = (size_t)b * SPAT;
  float ssum = 0.f, ssq = 0.f;

  stage_gload<2>(inbytes, brow, buf[0], ti0 * 64, wave, lane);

#pragma unroll
  for (int t = 0; t < TPW; ++t) {
    char* W = buf[t & 1];
    int p0 = (ti0 + t) * 64;
    if (t + 1 < TPW)
      stage_gload<2>(inbytes, brow, buf[(t + 1) & 1], (ti0 + t + 1) * 64, wave, lane);
    wait_vmcnt((t + 1 < TPW ? 6 : 0) + (t > 0 ? 6 : 0));   // gl(t) done
    bar_plain();                                           // tile visible

    f32x4 acc[3][4] = {};
    do_gemm<0>(W, w21b, wave, col, kg, acc);
    bar_plain();                                           // GEMM1 reads done
#pragma unroll
    for (int r = 0; r < 3; ++r) {
      int rowb = wave * 48 + r * 16 + kg * 4;
      f32x4 bs = *(const f32x4*)(b21 + rowb);
#pragma unroll
      for (int m = 0; m < 4; ++m) {
        int p = m * 16 + col;
        uint2 pk;
        pk.x = (unsigned)f2bf(acc[r][m][0] + bs[0]) | ((unsigned)f2bf(acc[r][m][1] + bs[1]) << 16);
        pk.y = (unsigned)f2bf(acc[r][m][2] + bs[2]) | ((unsigned)f2bf(acc[r][m][3] + bs[3]) << 16);
        *(uint2*)(W + lds_off(rowb >> 6, p, rowb & 63)) = pk;
      }
    }
    bar_lgkm();                                            // T visible
#pragma unroll
    for (int r = 0; r < 3; ++r)
#pragma unroll
      for (int m = 0; m < 4; ++m) acc[r][m] = (f32x4){0.f, 0.f, 0.f, 0.f};
    do_gemm<1>(W, w23b, wave, col, kg, acc);               // shiftW at read
    bar_plain();                                           // GEMM2 reads done
#pragma unroll
    for (int r = 0; r < 3; ++r) {
      int rowb = wave * 48 + r * 16 + kg * 4;
      f32x4 bs = *(const f32x4*)(b23 + rowb);
#pragma unroll
      for (int m = 0; m < 4; ++m) {
        int p = m * 16 + col;
        float v[4];
#pragma unroll
        for (int j = 0; j < 4; ++j) {
          float tv = gelu_exact(acc[r][m][j] + bs[j]);
          ssum += tv; ssq = fmaf(tv, tv, ssq);
          v[j] = tv;
        }
        uint2 pk;
        pk.x = (unsigned)f2bf(v[0]) | ((unsigned)f2bf(v[1]) << 16);
        pk.y = (unsigned)f2bf(v[2]) | ((unsigned)f2bf(v[3]) << 16);
        *(uint2*)(W + lds_off(rowb >> 6, p, rowb & 63)) = pk;
      }
    }
    bar_lgkm();                                            // out tile visible
    char* outbytes = (char*)outv + (brow + (size_t)p0) * 384;
#pragma unroll
    for (int j = 0; j < 6; ++j) {
      unsigned g = j * 256 + tid;
      int p = (int)(g / 24u), r24 = (int)(g - 24u * (unsigned)p);
      s16x8 v = *(const s16x8*)(W + lds_off(r24 >> 3, p, (r24 & 7) * 8));
      *(s16x8*)(outbytes + g * 16) = v;
    }
    bar_plain();   // all waves' store ds_reads done before gl(t+2) hits W
  }

#pragma unroll
  for (int off = 1; off < 64; off <<= 1) {
    ssum += __shfl_xor(ssum, off, 64);
    ssq += __shfl_xor(ssq, off, 64);
  }
  if (lane == 0) { red[wave][0] = ssum; red[wave][1] = ssq; }
  __syncthreads();
  if (tid == 0) {
    partials[wg * 2]     = red[0][0] + red[1][0] + red[2][0] + red[3][0];
    partials[wg * 2 + 1] = red[0][1] + red[1][1] + red[2][1] + red[3][1];
  }
}

// ---------------------------------------------------------------------------
// k3_pass: gload-staged, per-sample folded weights, f32 channel-major out.
// ---------------------------------------------------------------------------
__global__ __launch_bounds__(256, 3)
void k3_pass(const void* __restrict__ inv,
             const unsigned short* __restrict__ w3e,
             const float* __restrict__ b3e,
             float* __restrict__ outf) {
  __shared__ __align__(16) char buf[2][3 * 64 * 128];

  int wg = blockIdx.x;
  int b = wg / (TILES_ALL / TPW);
  int ti0 = (wg % (TILES_ALL / TPW)) * TPW;
  int tid = threadIdx.x;
  int wave = tid >> 6;
  int lane = tid & 63;
  int col = lane & 15;
  int kg = lane >> 4;

  const char* inbytes = (const char*)inv;
  size_t brow = (size_t)b * SPAT;
  const unsigned short* wbase = w3e + (size_t)b * NCH * NCH;
  const float* bbase = b3e + b * NCH;

  stage_gload<0>(inbytes, brow, buf[0], ti0 * 64, wave, lane);

#pragma unroll
  for (int t = 0; t < TPW; ++t) {
    char* W = buf[t & 1];
    int p0 = (ti0 + t) * 64;
    if (t + 1 < TPW)
      stage_gload<0>(inbytes, brow, buf[(t + 1) & 1], (ti0 + t + 1) * 64, wave, lane);
    wait_vmcnt((t + 1 < TPW ? 6 : 0) + (t > 0 ? 48 : 0));
    bar_plain();

    f32x4 acc[3][4] = {};
    do_gemm<0>(W, wbase, wave, col, kg, acc);
    bar_plain();   // reads done; gl(t+2) may now target W next iter

#pragma unroll
    for (int r = 0; r < 3; ++r) {
      int rowb = wave * 48 + r * 16 + kg * 4;
      f32x4 bs = *(const f32x4*)(bbase + rowb);
#pragma unroll
      for (int m = 0; m < 4; ++m) {
        int p = m * 16 + col;
#pragma unroll
        for (int j = 0; j < 4; ++j)
          outf[((size_t)b * NCH + rowb + j) * SPAT + p0 + p] = acc[r][m][j] + bs[j];
      }
    }
  }
}

// Deterministic per-sample stats finalize: nper partials per sample
__global__ void stats_finalize(const float* __restrict__ partials,
                               const float* __restrict__ nw,
                               const float* __restrict__ nb,
                               float* __restrict__ AC, int nper) {
  int b = blockIdx.x;
  int tid = threadIdx.x;
  __shared__ float s0[256], s1[256];
  float a = 0.f, c = 0.f;
  for (int i = tid; i < nper; i += 256) {
    a += partials[(b * nper + i) * 2];
    c += partials[(b * nper + i) * 2 + 1];
  }
  s0[tid] = a; s1[tid] = c;
  __syncthreads();
  for (int st = 128; st > 0; st >>= 1) {
    if (tid < st) { s0[tid] += s0[tid + st]; s1[tid] += s1[tid + st]; }
    __syncthreads();
  }
  float inv_n = 1.0f / (float)(NELEM_PER_B);
  float mu = s0[0] * inv_n;
  float var = s1[0] * inv_n - mu * mu;
  float rs = rsqrtf(var + 1e-5f);
  if (tid < NCH) {
    float A = rs * nw[tid];
    AC[b * 2 * NCH + tid] = A;
    AC[b * 2 * NCH + NCH + tid] = nb[tid] - mu * A;
  }
}

// fp32 -> bf16 weight conversion: slots 0=w1, 1=w22, 2=w21, 3=w23
__global__ void prep_weights(const float* __restrict__ w1, const float* __restrict__ w21,
                             const float* __restrict__ w22, const float* __restrict__ w23,
                             unsigned short* __restrict__ wb) {
  int i = blockIdx.x * 256 + threadIdx.x;
  if (i >= 4 * NCH * NCH) return;
  int m = i / (NCH * NCH), r = i % (NCH * NCH);
  const float* src = (m == 0) ? w1 : (m == 1) ? w22 : (m == 2) ? w21 : w23;
  wb[i] = f2bf(src[r]);
}

// Fold norm2 affine into w3/b3 per sample
__global__ void prep_w3(const float* __restrict__ w3, const float* __restrict__ b3,
                        const float* __restrict__ AC2,
                        unsigned short* __restrict__ w3e, float* __restrict__ b3e) {
  int b = blockIdx.x;
  int o = threadIdx.x;
  if (o >= NCH) return;
  const float* A = AC2 + b * 2 * NCH;
  const float* C = A + NCH;
  float s = b3[o];
  for (int c = 0; c < NCH; ++c) {
    float w = w3[o * NCH + c];
    w3e[((size_t)b * NCH + o) * NCH + c] = f2bf(w * A[c]);
    s = fmaf(w, C[c], s);
  }
  b3e[b * NCH + o] = s;
}

extern "C" void kernel_launch(void* const* d_in, const int* in_sizes, int n_in,
                              void* d_out, int out_size, void* d_ws, size_t ws_size,
                              hipStream_t stream) {
  const float* x   = (const float*)d_in[0];
  const float* w1  = (const float*)d_in[1];
  const float* b1  = (const float*)d_in[2];
  const float* n1w = (const float*)d_in[3];
  const float* n1b = (const float*)d_in[4];
  const float* w21 = (const float*)d_in[5];
  const float* b21 = (const float*)d_in[6];
  const float* w22 = (const float*)d_in[7];
  const float* b22 = (const float*)d_in[8];
  const float* w23 = (const float*)d_in[9];
  const float* b23 = (const float*)d_in[10];
  const float* n2w = (const float*)d_in[11];
  const float* n2b = (const float*)d_in[12];
  const float* w3  = (const float*)d_in[13];
  const float* b3  = (const float*)d_in[14];

  char* ws = (char*)d_ws;
  size_t off = 0;
  unsigned short* wb = (unsigned short*)(ws + off); off += (size_t)4 * NCH * NCH * 2;
  off = (off + 255) & ~(size_t)255;
  unsigned short* w3e = (unsigned short*)(ws + off); off += (size_t)NB * NCH * NCH * 2;
  off = (off + 255) & ~(size_t)255;
  float* b3e = (float*)(ws + off); off += NB * NCH * 4;
  float* AC1 = (float*)(ws + off); off += NB * 2 * NCH * 4;
  float* AC2 = (float*)(ws + off); off += NB * 2 * NCH * 4;
  float* part1 = (float*)(ws + off); off += (size_t)NB * TILES_ALL * 2 * 4;
  float* part2 = (float*)(ws + off); off += 1024 * 2 * 4;
  off = (off + 255) & ~(size_t)255;
  unsigned short* R1 = (unsigned short*)(ws + off);   // 100.7 MB bf16 (ws)
  unsigned short* R2 = (unsigned short*)d_out;        // bf16 scratch in d_out

  prep_weights<<<(4 * NCH * NCH + 255) / 256, 256, 0, stream>>>(w1, w21, w22, w23, wb);

  // K1: x (f32 cmajor) -> R1 via LDS transpose, W=w1, stats1  [R3-exact]
  simple_pass<0, 1, 1, 0><<<NB * TILES_ALL, 256, 0, stream>>>(
      x, wb + 0 * NCH * NCH, b1, R1, part1, nullptr);
  stats_finalize<<<NB, 256, 0, stream>>>(part1, n1w, n1b, AC1, TILES_ALL);

  // K2a: fused norm1+gelu staging, shift H(3), W=w22: R1 -> R2  [R3-exact]
  simple_pass<3, 0, 0, 1><<<NB * TILES_ALL, 256, 0, stream>>>(
      R1, wb + 1 * NCH * NCH, b22, R2, nullptr, AC1);

  // K2bc: gload shiftD stage -> w21 -> T -> shiftW -> w23 (+gelu+stats2): R2 -> R1
  k2bc_pass<<<NB * (TILES_ALL / TPW), 256, 0, stream>>>(
      R2, wb + 2 * NCH * NCH, b21, wb + 3 * NCH * NCH, b23, R1, part2);
  stats_finalize<<<NB, 256, 0, stream>>>(part2, n2w, n2b, AC2, TILES_ALL / TPW);
  prep_w3<<<NB, NCH, 0, stream>>>(w3, b3, AC2, w3e, b3e);

  // K3: gload stage, folded norm2+conv3, f32 cmajor out: R1 -> d_out
  k3_pass<<<NB * (TILES_ALL / TPW), 256, 0, stream>>>(
      R1, w3e, b3e, (float*)d_out);
}

// Round 8
// 482.003 us; speedup vs baseline: 1.3076x; 1.0732x over previous
//
#include <hip/hip_runtime.h>
#include <math.h>

#define NCH 192
#define NB 8
#define SPAT 32768                        // 32^3
#define TILES_PER_B 1024                  // 32-pos tiles (one W-row each)
#define NBLK (NB * TILES_PER_B)           // 8192 blocks per pass
#define NELEM_PER_B ((size_t)NCH * SPAT)  // 6291456

typedef short s16x8 __attribute__((ext_vector_type(8)));
typedef float f32x4 __attribute__((ext_vector_type(4)));

__device__ __forceinline__ float bf2f(unsigned short h) {
  return __uint_as_float(((unsigned)h) << 16);
}
__device__ __forceinline__ unsigned short f2bf(float f) {
  unsigned u = __float_as_uint(f);
  u += 0x7FFF + ((u >> 16) & 1);
  return (unsigned short)(u >> 16);
}
// packed RNE f32->bf16 pair in ONE instruction
__device__ __forceinline__ unsigned cvt_pk(float lo, float hi) {
  unsigned r;
  asm("v_cvt_pk_bf16_f32 %0, %1, %2" : "=v"(r) : "v"(lo), "v"(hi));
  return r;
}

// tanh-form GELU (max abs err vs exact erf-GELU ~5e-4; budget is 9.1e-2).
// 8 VALU ops: x2, fma, mul, fma(log2e), exp, add, rcp, fma.
__device__ __forceinline__ float gelu_f(float x) {
  float x2 = x * x;
  float z2 = x * fmaf(x2, 0.0713548163f, 1.5957769100f);  // 2*0.79788456*(x+0.044715x^3)/x
  float e = __expf(z2);                                   // e^{2z}
  float r = __builtin_amdgcn_rcpf(e + 1.0f);              // 1/(1+e^{2z})
  return fmaf(-r, x, x);                                  // x*(1-r) = 0.5x(1+tanh z)
}

// reflect-shift of an axis index by chunk c (s = c-1): j=i-s; -1->1, 32->30
__device__ __forceinline__ int rshift(int i, int c) {
  int j = i - (c - 1);
  j = (j < 0) ? 1 : j;
  j = (j > 31) ? 30 : j;
  return j;
}

// LDS tile [c:3][p:32][u:64] bf16, 128B rows; 16B-granule XOR swizzle
// granule' = (u>>3) ^ (p&7).  SINGLE helper for every LDS access (rule #21).
__device__ __forceinline__ int lds_off(int c, int p, int u) {
  return (c * 32 + p) * 128 + 16 * (((u >> 3) ^ (p & 7)) & 7) + 2 * (u & 7);
}

// 96-out-ch x 32-pos GEMM accumulate. A: weights from global (L2-resident),
// B: LDS tile. SHIFTW: W-axis reflect-shift at read (tile = one W-row).
template <int SHIFTW>
__device__ __forceinline__ void do_gemm96(const char* __restrict__ B,
                                          const unsigned short* __restrict__ wm,
                                          int wave, int col, int kg,
                                          f32x4 acc[6][2]) {
#pragma unroll
  for (int ks = 0; ks < 6; ++ks) {
    int k0 = ks * 32 + kg * 8;
    s16x8 af[6];
#pragma unroll
    for (int r = 0; r < 6; ++r)
      af[r] = *(const s16x8*)(wm + (wave * 96 + r * 16 + col) * NCH + k0);
    int c = k0 >> 6, u = k0 & 63;
    s16x8 bf[2];
#pragma unroll
    for (int m = 0; m < 2; ++m) {
      int p = m * 16 + col;
      int ps = SHIFTW ? rshift(p, c) : p;
      bf[m] = *(const s16x8*)(B + lds_off(c, ps, u));
    }
#pragma unroll
    for (int r = 0; r < 6; ++r)
#pragma unroll
      for (int m = 0; m < 2; ++m)
        acc[r][m] = __builtin_amdgcn_mfma_f32_16x16x32_bf16(af[r], bf[m], acc[r][m], 0, 0, 0);
  }
}

// block-level (2-wave) stats reduce -> partials[blk]
__device__ __forceinline__ void stats_reduce(float ssum, float ssq, int wave, int lane,
                                             float* red, float* partials, int blk) {
#pragma unroll
  for (int off = 1; off < 64; off <<= 1) {
    ssum += __shfl_xor(ssum, off, 64);
    ssq += __shfl_xor(ssq, off, 64);
  }
  if (lane == 0) { red[wave * 2] = ssum; red[wave * 2 + 1] = ssq; }
  __syncthreads();
  if (wave == 0 && lane == 0) {
    partials[blk * 2] = red[0] + red[2];
    partials[blk * 2 + 1] = red[1] + red[3];
  }
}

// ---------------------------------------------------------------------------
// pass1: x (f32 ch-major) -> conv(w1)+b1 -> bf16 [p][c], stats1
// ---------------------------------------------------------------------------
__global__ __launch_bounds__(128, 3)
void pass1(const float* __restrict__ x, const unsigned short* __restrict__ w1b,
           const float* __restrict__ b1, unsigned short* __restrict__ out,
           float* __restrict__ partials) {
  __shared__ __align__(16) char B[3 * 32 * 128];
  __shared__ __align__(16) char O[3 * 32 * 128];
  __shared__ float red[4];
  int blk = blockIdx.x, b = blk >> 10, p0 = (blk & 1023) * 32;
  int tid = threadIdx.x, wave = tid >> 6, lane = tid & 63;
  int col = lane & 15, kg = lane >> 4;

  // stage: f32 transpose-gather, pack ch-pairs, b32 LDS writes
  const float* xb = x + (size_t)b * NELEM_PER_B + p0;
  int pq = tid & 7;
#pragma unroll
  for (int j = 0; j < 6; ++j) {
    int chp = j * 16 + (tid >> 3);         // ch-pair index 0..95
    int ch0 = chp * 2;
    const int cc = j >> 1;                 // compile-time chunk
    const float* s0 = xb + (size_t)ch0 * SPAT + 4 * pq;
    f32x4 a = *(const f32x4*)s0;
    f32x4 c2 = *(const f32x4*)(s0 + SPAT);
    int u0 = ch0 & 63;
#pragma unroll
    for (int i = 0; i < 4; ++i)
      *(unsigned*)(B + lds_off(cc, 4 * pq + i, u0)) = cvt_pk(a[i], c2[i]);
  }
  __syncthreads();

  f32x4 acc[6][2] = {};
  do_gemm96<0>(B, w1b, wave, col, kg, acc);

  float ssum = 0.f, ssq = 0.f;
#pragma unroll
  for (int r = 0; r < 6; ++r) {
    int rowb = wave * 96 + r * 16 + kg * 4;
    f32x4 bs = *(const f32x4*)(b1 + rowb);
#pragma unroll
    for (int m = 0; m < 2; ++m) {
      int p = m * 16 + col;
      float v0 = acc[r][m][0] + bs[0], v1 = acc[r][m][1] + bs[1];
      float v2 = acc[r][m][2] + bs[2], v3 = acc[r][m][3] + bs[3];
      ssum += (v0 + v1) + (v2 + v3);
      ssq = fmaf(v0, v0, fmaf(v1, v1, fmaf(v2, v2, fmaf(v3, v3, ssq))));
      uint2 pk; pk.x = cvt_pk(v0, v1); pk.y = cvt_pk(v2, v3);
      *(uint2*)(O + lds_off(rowb >> 6, p, rowb & 63)) = pk;
    }
  }
  __syncthreads();
  char* ob = (char*)out + ((size_t)b * SPAT + p0) * 384;
  int G = tid & 7;
#pragma unroll
  for (int j = 0; j < 6; ++j) {
    const int c = j >> 1;
    int p = (j & 1) * 16 + (tid >> 3);
    s16x8 v = *(const s16x8*)(O + lds_off(c, p, G * 8));
    *(s16x8*)(ob + (size_t)p * 384 + (c * 8 + G) * 16) = v;
  }
  stats_reduce(ssum, ssq, wave, lane, red, partials, blk);
}

// ---------------------------------------------------------------------------
// pass2a: norm1-affine + GELU (fused at staging, bf16 A/C) + H-shift gather,
//         conv(w22)+b22 -> bf16 [p][c]
// ---------------------------------------------------------------------------
__global__ __launch_bounds__(128, 3)
void pass2a(const unsigned short* __restrict__ in, const unsigned short* __restrict__ w22b,
            const float* __restrict__ b22, unsigned short* __restrict__ out,
            const unsigned short* __restrict__ ACbf) {
  __shared__ __align__(16) char B[3 * 32 * 128];
  __shared__ __align__(16) char O[3 * 32 * 128];
  int blk = blockIdx.x, b = blk >> 10, p0 = (blk & 1023) * 32;
  int tid = threadIdx.x, wave = tid >> 6, lane = tid & 63;
  int col = lane & 15, kg = lane >> 4;

  int h = (p0 >> 5) & 31;
  int srow[3];
#pragma unroll
  for (int c = 0; c < 3; ++c) srow[c] = p0 + (rshift(h, c) - h) * 32;

  const char* ib = (const char*)in + (size_t)b * SPAT * 384;
  const unsigned short* acb = ACbf + b * 2 * NCH;
  int G = tid & 7;
#pragma unroll
  for (int j = 0; j < 6; ++j) {
    const int c = j >> 1;
    int p = (j & 1) * 16 + (tid >> 3);
    s16x8 v = *(const s16x8*)(ib + (size_t)(srow[c] + p) * 384 + (c * 8 + G) * 16);
    s16x8 aA = *(const s16x8*)(acb + c * 64 + G * 8);
    s16x8 aC = *(const s16x8*)(acb + NCH + c * 64 + G * 8);
    unsigned w[4];
#pragma unroll
    for (int i = 0; i < 4; ++i) {
      float f0 = gelu_f(fmaf(bf2f((unsigned short)v[2 * i]), bf2f((unsigned short)aA[2 * i]),
                             bf2f((unsigned short)aC[2 * i])));
      float f1 = gelu_f(fmaf(bf2f((unsigned short)v[2 * i + 1]), bf2f((unsigned short)aA[2 * i + 1]),
                             bf2f((unsigned short)aC[2 * i + 1])));
      w[i] = cvt_pk(f0, f1);
    }
    *(uint2*)(B + lds_off(c, p, G * 8)) = make_uint2(w[0], w[1]);
    *(uint2*)(B + lds_off(c, p, G * 8 + 4)) = make_uint2(w[2], w[3]);
  }
  __syncthreads();

  f32x4 acc[6][2] = {};
  do_gemm96<0>(B, w22b, wave, col, kg, acc);
#pragma unroll
  for (int r = 0; r < 6; ++r) {
    int rowb = wave * 96 + r * 16 + kg * 4;
    f32x4 bs = *(const f32x4*)(b22 + rowb);
#pragma unroll
    for (int m = 0; m < 2; ++m) {
      int p = m * 16 + col;
      uint2 pk;
      pk.x = cvt_pk(acc[r][m][0] + bs[0], acc[r][m][1] + bs[1]);
      pk.y = cvt_pk(acc[r][m][2] + bs[2], acc[r][m][3] + bs[3]);
      *(uint2*)(O + lds_off(rowb >> 6, p, rowb & 63)) = pk;
    }
  }
  __syncthreads();
  char* ob = (char*)out + ((size_t)b * SPAT + p0) * 384;
#pragma unroll
  for (int j = 0; j < 6; ++j) {
    const int c = j >> 1;
    int p = (j & 1) * 16 + (tid >> 3);
    s16x8 v = *(const s16x8*)(O + lds_off(c, p, G * 8));
    *(s16x8*)(ob + (size_t)p * 384 + (c * 8 + G) * 16) = v;
  }
}

// ---------------------------------------------------------------------------
// pass2bc: D-shift gather -> conv(w21)+b21 -> T(LDS) -> W-shift read ->
//          conv(w23)+b23 -> GELU -> stats2 -> bf16 [p][c]
// ---------------------------------------------------------------------------
__global__ __launch_bounds__(128, 3)
void pass2bc(const unsigned short* __restrict__ in, const unsigned short* __restrict__ w21b,
             const float* __restrict__ b21, const unsigned short* __restrict__ w23b,
             const float* __restrict__ b23, unsigned short* __restrict__ out,
             float* __restrict__ partials) {
  __shared__ __align__(16) char B[3 * 32 * 128];
  __shared__ __align__(16) char O[3 * 32 * 128];
  __shared__ float red[4];
  int blk = blockIdx.x, b = blk >> 10, p0 = (blk & 1023) * 32;
  int tid = threadIdx.x, wave = tid >> 6, lane = tid & 63;
  int col = lane & 15, kg = lane >> 4;

  int d = p0 >> 10;
  int srow[3];
#pragma unroll
  for (int c = 0; c < 3; ++c) srow[c] = p0 + (rshift(d, c) - d) * 1024;

  const char* ib = (const char*)in + (size_t)b * SPAT * 384;
  int G = tid & 7;
#pragma unroll
  for (int j = 0; j < 6; ++j) {
    const int c = j >> 1;
    int p = (j & 1) * 16 + (tid >> 3);
    s16x8 v = *(const s16x8*)(ib + (size_t)(srow[c] + p) * 384 + (c * 8 + G) * 16);
    *(s16x8*)(B + lds_off(c, p, G * 8)) = v;
  }
  __syncthreads();                       // B visible

  f32x4 acc[6][2] = {};
  do_gemm96<0>(B, w21b, wave, col, kg, acc);
#pragma unroll
  for (int r = 0; r < 6; ++r) {
    int rowb = wave * 96 + r * 16 + kg * 4;
    f32x4 bs = *(const f32x4*)(b21 + rowb);
#pragma unroll
    for (int m = 0; m < 2; ++m) {
      int p = m * 16 + col;
      uint2 pk;
      pk.x = cvt_pk(acc[r][m][0] + bs[0], acc[r][m][1] + bs[1]);
      pk.y = cvt_pk(acc[r][m][2] + bs[2], acc[r][m][3] + bs[3]);
      *(uint2*)(O + lds_off(rowb >> 6, p, rowb & 63)) = pk;
    }
  }
  __syncthreads();                       // T visible (both waves past GEMM1)

#pragma unroll
  for (int r = 0; r < 6; ++r)
#pragma unroll
    for (int m = 0; m < 2; ++m) acc[r][m] = (f32x4){0.f, 0.f, 0.f, 0.f};
  do_gemm96<1>(O, w23b, wave, col, kg, acc);   // W-shift at read

  float ssum = 0.f, ssq = 0.f;
#pragma unroll
  for (int r = 0; r < 6; ++r) {
    int rowb = wave * 96 + r * 16 + kg * 4;
    f32x4 bs = *(const f32x4*)(b23 + rowb);
#pragma unroll
    for (int m = 0; m < 2; ++m) {
      int p = m * 16 + col;
      float v0 = gelu_f(acc[r][m][0] + bs[0]), v1 = gelu_f(acc[r][m][1] + bs[1]);
      float v2 = gelu_f(acc[r][m][2] + bs[2]), v3 = gelu_f(acc[r][m][3] + bs[3]);
      ssum += (v0 + v1) + (v2 + v3);
      ssq = fmaf(v0, v0, fmaf(v1, v1, fmaf(v2, v2, fmaf(v3, v3, ssq))));
      uint2 pk; pk.x = cvt_pk(v0, v1); pk.y = cvt_pk(v2, v3);
      *(uint2*)(B + lds_off(rowb >> 6, p, rowb & 63)) = pk;   // B is dead
    }
  }
  __syncthreads();                       // out tile visible
  char* ob = (char*)out + ((size_t)b * SPAT + p0) * 384;
#pragma unroll
  for (int j = 0; j < 6; ++j) {
    const int c = j >> 1;
    int p = (j & 1) * 16 + (tid >> 3);
    s16x8 v = *(const s16x8*)(B + lds_off(c, p, G * 8));
    *(s16x8*)(ob + (size_t)p * 384 + (c * 8 + G) * 16) = v;
  }
  stats_reduce(ssum, ssq, wave, lane, red, partials, blk);
}

// ---------------------------------------------------------------------------
// pass3: conv(w3e per-sample folded norm2) + b3e -> f32 channel-major d_out
// ---------------------------------------------------------------------------
__global__ __launch_bounds__(128, 4)
void pass3(const unsigned short* __restrict__ in, const unsigned short* __restrict__ w3e,
           const float* __restrict__ b3e, float* __restrict__ outf) {
  __shared__ __align__(16) char B[3 * 32 * 128];
  int blk = blockIdx.x, b = blk >> 10, p0 = (blk & 1023) * 32;
  int tid = threadIdx.x, wave = tid >> 6, lane = tid & 63;
  int col = lane & 15, kg = lane >> 4;

  const char* ib = (const char*)in + (size_t)b * SPAT * 384;
  int G = tid & 7;
#pragma unroll
  for (int j = 0; j < 6; ++j) {
    const int c = j >> 1;
    int p = (j & 1) * 16 + (tid >> 3);
    s16x8 v = *(const s16x8*)(ib + (size_t)(p0 + p) * 384 + (c * 8 + G) * 16);
    *(s16x8*)(B + lds_off(c, p, G * 8)) = v;
  }
  __syncthreads();

  f32x4 acc[6][2] = {};
  do_gemm96<0>(B, w3e + (size_t)b * NCH * NCH, wave, col, kg, acc);

  const float* bb = b3e + b * NCH;
#pragma unroll
  for (int r = 0; r < 6; ++r) {
    int rowb = wave * 96 + r * 16 + kg * 4;
    f32x4 bs = *(const f32x4*)(bb + rowb);
#pragma unroll
    for (int m = 0; m < 2; ++m) {
      int p = p0 + m * 16 + col;
#pragma unroll
      for (int j = 0; j < 4; ++j)
        outf[((size_t)b * NCH + rowb + j) * SPAT + p] = acc[r][m][j] + bs[j];
    }
  }
}

// Deterministic stats finalize: 1024 partials/sample -> f32 AC + bf16 ACbf
__global__ void stats_finalize(const float* __restrict__ partials,
                               const float* __restrict__ nw, const float* __restrict__ nb,
                               float* __restrict__ AC, unsigned short* __restrict__ ACbf) {
  int b = blockIdx.x, tid = threadIdx.x;
  __shared__ float s0[256], s1[256];
  float a = 0.f, c = 0.f;
  for (int i = tid; i < TILES_PER_B; i += 256) {
    a += partials[(b * TILES_PER_B + i) * 2];
    c += partials[(b * TILES_PER_B + i) * 2 + 1];
  }
  s0[tid] = a; s1[tid] = c;
  __syncthreads();
  for (int st = 128; st > 0; st >>= 1) {
    if (tid < st) { s0[tid] += s0[tid + st]; s1[tid] += s1[tid + st]; }
    __syncthreads();
  }
  float inv_n = 1.0f / (float)NELEM_PER_B;
  float mu = s0[0] * inv_n;
  float var = s1[0] * inv_n - mu * mu;
  float rs = rsqrtf(var + 1e-5f);
  if (tid < NCH) {
    float A = rs * nw[tid];
    float C = nb[tid] - mu * A;
    AC[b * 2 * NCH + tid] = A;
    AC[b * 2 * NCH + NCH + tid] = C;
    ACbf[b * 2 * NCH + tid] = f2bf(A);
    ACbf[b * 2 * NCH + NCH + tid] = f2bf(C);
  }
}

__global__ void prep_weights(const float* __restrict__ w1, const float* __restrict__ w21,
                             const float* __restrict__ w22, const float* __restrict__ w23,
                             unsigned short* __restrict__ wb) {
  int i = blockIdx.x * 256 + threadIdx.x;
  if (i >= 4 * NCH * NCH) return;
  int m = i / (NCH * NCH), r = i % (NCH * NCH);
  const float* src = (m == 0) ? w1 : (m == 1) ? w22 : (m == 2) ? w21 : w23;
  wb[i] = f2bf(src[r]);
}

__global__ void prep_w3(const float* __restrict__ w3, const float* __restrict__ b3,
                        const float* __restrict__ AC2,
                        unsigned short* __restrict__ w3e, float* __restrict__ b3e) {
  int b = blockIdx.x, o = threadIdx.x;
  if (o >= NCH) return;
  const float* A = AC2 + b * 2 * NCH;
  const float* C = A + NCH;
  float s = b3[o];
  for (int c = 0; c < NCH; ++c) {
    float w = w3[o * NCH + c];
    w3e[((size_t)b * NCH + o) * NCH + c] = f2bf(w * A[c]);
    s = fmaf(w, C[c], s);
  }
  b3e[b * NCH + o] = s;
}

extern "C" void kernel_launch(void* const* d_in, const int* in_sizes, int n_in,
                              void* d_out, int out_size, void* d_ws, size_t ws_size,
                              hipStream_t stream) {
  const float* x   = (const float*)d_in[0];
  const float* w1  = (const float*)d_in[1];
  const float* b1  = (const float*)d_in[2];
  const float* n1w = (const float*)d_in[3];
  const float* n1b = (const float*)d_in[4];
  const float* w21 = (const float*)d_in[5];
  const float* b21 = (const float*)d_in[6];
  const float* w22 = (const float*)d_in[7];
  const float* b22 = (const float*)d_in[8];
  const float* w23 = (const float*)d_in[9];
  const float* b23 = (const float*)d_in[10];
  const float* n2w = (const float*)d_in[11];
  const float* n2b = (const float*)d_in[12];
  const float* w3  = (const float*)d_in[13];
  const float* b3  = (const float*)d_in[14];

  char* ws = (char*)d_ws;
  size_t off = 0;
  unsigned short* wb = (unsigned short*)(ws + off); off += (size_t)4 * NCH * NCH * 2;
  off = (off + 255) & ~(size_t)255;
  unsigned short* w3e = (unsigned short*)(ws + off); off += (size_t)NB * NCH * NCH * 2;
  off = (off + 255) & ~(size_t)255;
  float* b3e = (float*)(ws + off); off += NB * NCH * 4;
  float* AC1 = (float*)(ws + off); off += NB * 2 * NCH * 4;
  float* AC2 = (float*)(ws + off); off += NB * 2 * NCH * 4;
  unsigned short* ACbf1 = (unsigned short*)(ws + off); off += NB * 2 * NCH * 2;
  unsigned short* ACbf2 = (unsigned short*)(ws + off); off += NB * 2 * NCH * 2;
  off = (off + 255) & ~(size_t)255;
  float* part1 = (float*)(ws + off); off += (size_t)NBLK * 2 * 4;
  float* part2 = (float*)(ws + off); off += (size_t)NBLK * 2 * 4;
  off = (off + 255) & ~(size_t)255;
  unsigned short* R1 = (unsigned short*)(ws + off);   // 100.7 MB bf16 (ws)
  unsigned short* R2 = (unsigned short*)d_out;        // bf16 scratch in d_out

  prep_weights<<<(4 * NCH * NCH + 255) / 256, 256, 0, stream>>>(w1, w21, w22, w23, wb);

  // K1: x -> R1 (conv w1 + b1), stats1
  pass1<<<NBLK, 128, 0, stream>>>(x, wb + 0 * NCH * NCH, b1, R1, part1);
  stats_finalize<<<NB, 256, 0, stream>>>(part1, n1w, n1b, AC1, ACbf1);

  // K2a: norm1+gelu fused staging, H-shift, conv w22 + b22: R1 -> R2
  pass2a<<<NBLK, 128, 0, stream>>>(R1, wb + 1 * NCH * NCH, b22, R2, ACbf1);

  // K2bc: D-shift stage -> w21 -> T -> W-shift -> w23 + gelu + stats2: R2 -> R1
  pass2bc<<<NBLK, 128, 0, stream>>>(R2, wb + 2 * NCH * NCH, b21,
                                    wb + 3 * NCH * NCH, b23, R1, part2);
  stats_finalize<<<NB, 256, 0, stream>>>(part2, n2w, n2b, AC2, ACbf2);
  prep_w3<<<NB, NCH, 0, stream>>>(w3, b3, AC2, w3e, b3e);

  // K3: folded norm2 + conv w3: R1 -> d_out (f32 channel-major)
  pass3<<<NBLK, 128, 0, stream>>>(R1, w3e, b3e, (float*)d_out);
}

// Round 9
// 334.458 us; speedup vs baseline: 1.8844x; 1.4411x over previous
//
#include <hip/hip_runtime.h>
#include <math.h>

#define NCH 192
#define NB 8
#define SPAT 32768                        // 32^3
#define TILES_PER_B 512                   // 64-pos tiles per sample
#define NBLK (NB * TILES_PER_B)           // 4096 blocks per pass
#define NELEM_PER_B ((size_t)NCH * SPAT)  // 6291456

typedef short s16x8 __attribute__((ext_vector_type(8)));
typedef float f32x4 __attribute__((ext_vector_type(4)));

__device__ __forceinline__ float bf2f(unsigned short h) {
  return __uint_as_float(((unsigned)h) << 16);
}
__device__ __forceinline__ unsigned short f2bf(float f) {
  unsigned u = __float_as_uint(f);
  u += 0x7FFF + ((u >> 16) & 1);
  return (unsigned short)(u >> 16);
}
// packed RNE f32->bf16 pair in ONE instruction
__device__ __forceinline__ unsigned cvt_pk(float lo, float hi) {
  unsigned r;
  asm("v_cvt_pk_bf16_f32 %0, %1, %2" : "=v"(r) : "v"(lo), "v"(hi));
  return r;
}

// tanh-form GELU (max abs err ~5e-4; budget 9.1e-2).  ~8 VALU ops.
__device__ __forceinline__ float gelu_f(float x) {
  float x2 = x * x;
  float z2 = x * fmaf(x2, 0.0713548163f, 1.5957769100f);
  float e = __expf(z2);
  float r = __builtin_amdgcn_rcpf(e + 1.0f);
  return fmaf(-r, x, x);
}

// reflect-shift of axis index i by chunk c (shift s = c-1): -1->1, 32->30
__device__ __forceinline__ int rshift(int i, int c) {
  int j = i - (c - 1);
  j = (j < 0) ? 1 : j;
  j = (j > 31) ? 30 : j;
  return j;
}

// LDS tile [c:3][p:64][u:64] bf16 (128B rows); 16B-granule XOR swizzle
// granule' = (u>>3) ^ (p&7) ^ ((p>>3)&7).  SINGLE helper everywhere (rule #21).
__device__ __forceinline__ int lds_off(int c, int p, int u) {
  return (c * 64 + p) * 128 + 16 * (((u >> 3) ^ (p & 7) ^ ((p >> 3) & 7)) & 7) + 2 * (u & 7);
}

// 48-out-ch-per-wave x 64-pos GEMM with 2-DEEP PIPELINED weight fragments:
// af loads for ks+1 are issued before the MFMAs of ks, so the L2 latency of
// the weight reads is covered by the MFMA+ds_read work of the previous step
// (counted vmcnt, never a full drain).  SHIFTW: W-axis reflect-shift at read.
template <int SHIFTW>
__device__ __forceinline__ void do_gemm48(const char* __restrict__ B,
                                          const unsigned short* __restrict__ wm,
                                          int wave, int col, int kg,
                                          f32x4 acc[3][4]) {
  const unsigned short* wp = wm + (wave * 48 + col) * NCH + kg * 8;
  s16x8 afc[3], afn[3];
#pragma unroll
  for (int r = 0; r < 3; ++r) afc[r] = *(const s16x8*)(wp + r * 16 * NCH);
#pragma unroll
  for (int ks = 0; ks < 6; ++ks) {
    if (ks < 5) {
#pragma unroll
      for (int r = 0; r < 3; ++r)
        afn[r] = *(const s16x8*)(wp + (ks + 1) * 32 + r * 16 * NCH);
    }
    int k0 = ks * 32 + kg * 8;
    int c = k0 >> 6, u = k0 & 63;
    s16x8 bf[4];
#pragma unroll
    for (int m = 0; m < 4; ++m) {
      int p = m * 16 + col;
      int ps = SHIFTW ? ((p & 32) | rshift(p & 31, c)) : p;
      bf[m] = *(const s16x8*)(B + lds_off(c, ps, u));
    }
#pragma unroll
    for (int r = 0; r < 3; ++r)
#pragma unroll
      for (int m = 0; m < 4; ++m)
        acc[r][m] = __builtin_amdgcn_mfma_f32_16x16x32_bf16(afc[r], bf[m], acc[r][m], 0, 0, 0);
#pragma unroll
    for (int r = 0; r < 3; ++r) afc[r] = afn[r];
  }
}

// block (4-wave) stats reduce -> partials[blk]
__device__ __forceinline__ void stats_reduce(float ssum, float ssq, int wave, int lane,
                                             float* red, float* partials, int blk) {
#pragma unroll
  for (int off = 1; off < 64; off <<= 1) {
    ssum += __shfl_xor(ssum, off, 64);
    ssq += __shfl_xor(ssq, off, 64);
  }
  if (lane == 0) { red[wave * 2] = ssum; red[wave * 2 + 1] = ssq; }
  __syncthreads();
  if (wave == 0 && lane == 0) {
    partials[blk * 2] = red[0] + red[2] + red[4] + red[6];
    partials[blk * 2 + 1] = red[1] + red[3] + red[5] + red[7];
  }
}

// coop store: LDS tile -> bf16 [p][c] global (contiguous 24KB)
__device__ __forceinline__ void store_tile(const char* __restrict__ L, char* __restrict__ ob,
                                           int tid) {
  int G = tid & 7;
#pragma unroll
  for (int j = 0; j < 6; ++j) {
    const int c = j >> 1;
    int p = (j & 1) * 32 + (tid >> 3);
    s16x8 v = *(const s16x8*)(L + lds_off(c, p, G * 8));
    *(s16x8*)(ob + (size_t)p * 384 + (c * 8 + G) * 16) = v;
  }
}

// ---------------------------------------------------------------------------
// pass1: x (f32 ch-major) -> conv(w1)+b1 -> bf16 [p][c], stats1
// ---------------------------------------------------------------------------
__global__ __launch_bounds__(256, 4)
void pass1(const float* __restrict__ x, const unsigned short* __restrict__ w1b,
           const float* __restrict__ b1, unsigned short* __restrict__ out,
           float* __restrict__ partials) {
  __shared__ __align__(16) char B[3 * 64 * 128];
  __shared__ float red[8];
  int blk = blockIdx.x, b = blk >> 9, p0 = (blk & 511) * 64;
  int tid = threadIdx.x, wave = tid >> 6, lane = tid & 63;
  int col = lane & 15, kg = lane >> 4;

  // stage: f32 transpose-gather of ch-pairs, packed b32 writes
  const float* xb = x + (size_t)b * NELEM_PER_B + p0;
  int q = tid & 15;
#pragma unroll
  for (int j = 0; j < 6; ++j) {
    int chp = j * 16 + (tid >> 4);          // ch-pair 0..95
    int ch0 = 2 * chp;
    int cc = chp >> 5, u0 = ch0 & 63;
    const float* s0 = xb + (size_t)ch0 * SPAT + 4 * q;
    f32x4 a = *(const f32x4*)s0;
    f32x4 c2 = *(const f32x4*)(s0 + SPAT);
#pragma unroll
    for (int i = 0; i < 4; ++i)
      *(unsigned*)(B + lds_off(cc, 4 * q + i, u0)) = cvt_pk(a[i], c2[i]);
  }
  __syncthreads();

  f32x4 acc[3][4] = {};
  do_gemm48<0>(B, w1b, wave, col, kg, acc);

  float ssum = 0.f, ssq = 0.f;
  __syncthreads();   // all B reads done; reuse as output tile
#pragma unroll
  for (int r = 0; r < 3; ++r) {
    int rowb = wave * 48 + r * 16 + kg * 4;
    f32x4 bs = *(const f32x4*)(b1 + rowb);
#pragma unroll
    for (int m = 0; m < 4; ++m) {
      int p = m * 16 + col;
      float v0 = acc[r][m][0] + bs[0], v1 = acc[r][m][1] + bs[1];
      float v2 = acc[r][m][2] + bs[2], v3 = acc[r][m][3] + bs[3];
      ssum += (v0 + v1) + (v2 + v3);
      ssq = fmaf(v0, v0, fmaf(v1, v1, fmaf(v2, v2, fmaf(v3, v3, ssq))));
      uint2 pk; pk.x = cvt_pk(v0, v1); pk.y = cvt_pk(v2, v3);
      *(uint2*)(B + lds_off(rowb >> 6, p, rowb & 63)) = pk;
    }
  }
  __syncthreads();
  store_tile(B, (char*)out + ((size_t)b * SPAT + p0) * 384, tid);
  stats_reduce(ssum, ssq, wave, lane, red, partials, blk);
}

// ---------------------------------------------------------------------------
// pass2a: H-shift gather + fused norm1-affine+GELU, conv(w22)+b22 -> bf16
// ---------------------------------------------------------------------------
__global__ __launch_bounds__(256, 4)
void pass2a(const unsigned short* __restrict__ in, const unsigned short* __restrict__ w22b,
            const float* __restrict__ b22, unsigned short* __restrict__ out,
            const unsigned short* __restrict__ ACbf) {
  __shared__ __align__(16) char B[3 * 64 * 128];
  int blk = blockIdx.x, b = blk >> 9, p0 = (blk & 511) * 64;
  int tid = threadIdx.x, wave = tid >> 6, lane = tid & 63;
  int col = lane & 15, kg = lane >> 4;

  const char* ib = (const char*)in + (size_t)b * SPAT * 384;
  const unsigned short* acb = ACbf + b * 2 * NCH;
  int G = tid & 7;
#pragma unroll
  for (int j = 0; j < 6; ++j) {
    const int c = j >> 1;
    int p = (j & 1) * 32 + (tid >> 3);
    int h = ((p0 + p) >> 5) & 31;
    int sp = (p0 + p) + (rshift(h, c) - h) * 32;
    s16x8 v = *(const s16x8*)(ib + (size_t)sp * 384 + (c * 8 + G) * 16);
    s16x8 aA = *(const s16x8*)(acb + c * 64 + G * 8);
    s16x8 aC = *(const s16x8*)(acb + NCH + c * 64 + G * 8);
    unsigned w[4];
#pragma unroll
    for (int i = 0; i < 4; ++i) {
      float f0 = gelu_f(fmaf(bf2f((unsigned short)v[2 * i]), bf2f((unsigned short)aA[2 * i]),
                             bf2f((unsigned short)aC[2 * i])));
      float f1 = gelu_f(fmaf(bf2f((unsigned short)v[2 * i + 1]), bf2f((unsigned short)aA[2 * i + 1]),
                             bf2f((unsigned short)aC[2 * i + 1])));
      w[i] = cvt_pk(f0, f1);
    }
    *(uint2*)(B + lds_off(c, p, G * 8)) = make_uint2(w[0], w[1]);
    *(uint2*)(B + lds_off(c, p, G * 8 + 4)) = make_uint2(w[2], w[3]);
  }
  __syncthreads();

  f32x4 acc[3][4] = {};
  do_gemm48<0>(B, w22b, wave, col, kg, acc);
  __syncthreads();
#pragma unroll
  for (int r = 0; r < 3; ++r) {
    int rowb = wave * 48 + r * 16 + kg * 4;
    f32x4 bs = *(const f32x4*)(b22 + rowb);
#pragma unroll
    for (int m = 0; m < 4; ++m) {
      int p = m * 16 + col;
      uint2 pk;
      pk.x = cvt_pk(acc[r][m][0] + bs[0], acc[r][m][1] + bs[1]);
      pk.y = cvt_pk(acc[r][m][2] + bs[2], acc[r][m][3] + bs[3]);
      *(uint2*)(B + lds_off(rowb >> 6, p, rowb & 63)) = pk;
    }
  }
  __syncthreads();
  store_tile(B, (char*)out + ((size_t)b * SPAT + p0) * 384, tid);
}

// ---------------------------------------------------------------------------
// pass2bc: D-shift gather -> conv(w21)+b21 -> T (in-place LDS) -> W-shift
//          read -> conv(w23)+b23 -> GELU -> stats2 -> bf16 [p][c]
// ---------------------------------------------------------------------------
__global__ __launch_bounds__(256, 4)
void pass2bc(const unsigned short* __restrict__ in, const unsigned short* __restrict__ w21b,
             const float* __restrict__ b21, const unsigned short* __restrict__ w23b,
             const float* __restrict__ b23, unsigned short* __restrict__ out,
             float* __restrict__ partials) {
  __shared__ __align__(16) char B[3 * 64 * 128];
  __shared__ float red[8];
  int blk = blockIdx.x, b = blk >> 9, p0 = (blk & 511) * 64;
  int tid = threadIdx.x, wave = tid >> 6, lane = tid & 63;
  int col = lane & 15, kg = lane >> 4;

  int d = p0 >> 10;
  int soff[3];
#pragma unroll
  for (int c = 0; c < 3; ++c) soff[c] = (rshift(d, c) - d) * 1024;

  const char* ib = (const char*)in + (size_t)b * SPAT * 384;
  int G = tid & 7;
#pragma unroll
  for (int j = 0; j < 6; ++j) {
    const int c = j >> 1;
    int p = (j & 1) * 32 + (tid >> 3);
    s16x8 v = *(const s16x8*)(ib + (size_t)(p0 + p + soff[c]) * 384 + (c * 8 + G) * 16);
    *(s16x8*)(B + lds_off(c, p, G * 8)) = v;
  }
  __syncthreads();                         // B visible

  f32x4 acc[3][4] = {};
  do_gemm48<0>(B, w21b, wave, col, kg, acc);
  __syncthreads();                         // GEMM1 reads done
#pragma unroll
  for (int r = 0; r < 3; ++r) {
    int rowb = wave * 48 + r * 16 + kg * 4;
    f32x4 bs = *(const f32x4*)(b21 + rowb);
#pragma unroll
    for (int m = 0; m < 4; ++m) {
      int p = m * 16 + col;
      uint2 pk;
      pk.x = cvt_pk(acc[r][m][0] + bs[0], acc[r][m][1] + bs[1]);
      pk.y = cvt_pk(acc[r][m][2] + bs[2], acc[r][m][3] + bs[3]);
      *(uint2*)(B + lds_off(rowb >> 6, p, rowb & 63)) = pk;
    }
  }
  __syncthreads();                         // T visible

#pragma unroll
  for (int r = 0; r < 3; ++r)
#pragma unroll
    for (int m = 0; m < 4; ++m) acc[r][m] = (f32x4){0.f, 0.f, 0.f, 0.f};
  do_gemm48<1>(B, w23b, wave, col, kg, acc);   // W-shift at read
  __syncthreads();                         // GEMM2 reads done

  float ssum = 0.f, ssq = 0.f;
#pragma unroll
  for (int r = 0; r < 3; ++r) {
    int rowb = wave * 48 + r * 16 + kg * 4;
    f32x4 bs = *(const f32x4*)(b23 + rowb);
#pragma unroll
    for (int m = 0; m < 4; ++m) {
      int p = m * 16 + col;
      float v0 = gelu_f(acc[r][m][0] + bs[0]), v1 = gelu_f(acc[r][m][1] + bs[1]);
      float v2 = gelu_f(acc[r][m][2] + bs[2]), v3 = gelu_f(acc[r][m][3] + bs[3]);
      ssum += (v0 + v1) + (v2 + v3);
      ssq = fmaf(v0, v0, fmaf(v1, v1, fmaf(v2, v2, fmaf(v3, v3, ssq))));
      uint2 pk; pk.x = cvt_pk(v0, v1); pk.y = cvt_pk(v2, v3);
      *(uint2*)(B + lds_off(rowb >> 6, p, rowb & 63)) = pk;
    }
  }
  __syncthreads();                         // out tile visible
  store_tile(B, (char*)out + ((size_t)b * SPAT + p0) * 384, tid);
  stats_reduce(ssum, ssq, wave, lane, red, partials, blk);
}

// ---------------------------------------------------------------------------
// pass3: conv(w3e per-sample folded norm2)+b3e -> f32 channel-major d_out
// ---------------------------------------------------------------------------
__global__ __launch_bounds__(256, 4)
void pass3(const unsigned short* __restrict__ in, const unsigned short* __restrict__ w3e,
           const float* __restrict__ b3e, float* __restrict__ outf) {
  __shared__ __align__(16) char B[3 * 64 * 128];
  int blk = blockIdx.x, b = blk >> 9, p0 = (blk & 511) * 64;
  int tid = threadIdx.x, wave = tid >> 6, lane = tid & 63;
  int col = lane & 15, kg = lane >> 4;

  const char* ib = (const char*)in + (size_t)b * SPAT * 384;
  int G = tid & 7;
#pragma unroll
  for (int j = 0; j < 6; ++j) {
    const int c = j >> 1;
    int p = (j & 1) * 32 + (tid >> 3);
    s16x8 v = *(const s16x8*)(ib + (size_t)(p0 + p) * 384 + (c * 8 + G) * 16);
    *(s16x8*)(B + lds_off(c, p, G * 8)) = v;
  }
  __syncthreads();

  f32x4 acc[3][4] = {};
  do_gemm48<0>(B, w3e + (size_t)b * NCH * NCH, wave, col, kg, acc);

  const float* bb = b3e + b * NCH;
#pragma unroll
  for (int r = 0; r < 3; ++r) {
    int rowb = wave * 48 + r * 16 + kg * 4;
    f32x4 bs = *(const f32x4*)(bb + rowb);
#pragma unroll
    for (int m = 0; m < 4; ++m) {
      int p = p0 + m * 16 + col;
#pragma unroll
      for (int j = 0; j < 4; ++j)
        outf[((size_t)b * NCH + rowb + j) * SPAT + p] = acc[r][m][j] + bs[j];
    }
  }
}

// Deterministic stats finalize: 512 partials/sample -> f32 AC + bf16 ACbf
__global__ void stats_finalize(const float* __restrict__ partials,
                               const float* __restrict__ nw, const float* __restrict__ nb,
                               float* __restrict__ AC, unsigned short* __restrict__ ACbf) {
  int b = blockIdx.x, tid = threadIdx.x;
  __shared__ float s0[256], s1[256];
  float a = 0.f, c = 0.f;
  for (int i = tid; i < TILES_PER_B; i += 256) {
    a += partials[(b * TILES_PER_B + i) * 2];
    c += partials[(b * TILES_PER_B + i) * 2 + 1];
  }
  s0[tid] = a; s1[tid] = c;
  __syncthreads();
  for (int st = 128; st > 0; st >>= 1) {
    if (tid < st) { s0[tid] += s0[tid + st]; s1[tid] += s1[tid + st]; }
    __syncthreads();
  }
  float inv_n = 1.0f / (float)NELEM_PER_B;
  float mu = s0[0] * inv_n;
  float var = s1[0] * inv_n - mu * mu;
  float rs = rsqrtf(var + 1e-5f);
  if (tid < NCH) {
    float A = rs * nw[tid];
    float C = nb[tid] - mu * A;
    AC[b * 2 * NCH + tid] = A;
    AC[b * 2 * NCH + NCH + tid] = C;
    ACbf[b * 2 * NCH + tid] = f2bf(A);
    ACbf[b * 2 * NCH + NCH + tid] = f2bf(C);
  }
}

__global__ void prep_weights(const float* __restrict__ w1, const float* __restrict__ w21,
                             const float* __restrict__ w22, const float* __restrict__ w23,
                             unsigned short* __restrict__ wb) {
  int i = blockIdx.x * 256 + threadIdx.x;
  if (i >= 4 * NCH * NCH) return;
  int m = i / (NCH * NCH), r = i % (NCH * NCH);
  const float* src = (m == 0) ? w1 : (m == 1) ? w22 : (m == 2) ? w21 : w23;
  wb[i] = f2bf(src[r]);
}

__global__ void prep_w3(const float* __restrict__ w3, const float* __restrict__ b3,
                        const float* __restrict__ AC2,
                        unsigned short* __restrict__ w3e, float* __restrict__ b3e) {
  int b = blockIdx.x, o = threadIdx.x;
  if (o >= NCH) return;
  const float* A = AC2 + b * 2 * NCH;
  const float* C = A + NCH;
  float s = b3[o];
  for (int c = 0; c < NCH; ++c) {
    float w = w3[o * NCH + c];
    w3e[((size_t)b * NCH + o) * NCH + c] = f2bf(w * A[c]);
    s = fmaf(w, C[c], s);
  }
  b3e[b * NCH + o] = s;
}

extern "C" void kernel_launch(void* const* d_in, const int* in_sizes, int n_in,
                              void* d_out, int out_size, void* d_ws, size_t ws_size,
                              hipStream_t stream) {
  const float* x   = (const float*)d_in[0];
  const float* w1  = (const float*)d_in[1];
  const float* b1  = (const float*)d_in[2];
  const float* n1w = (const float*)d_in[3];
  const float* n1b = (const float*)d_in[4];
  const float* w21 = (const float*)d_in[5];
  const float* b21 = (const float*)d_in[6];
  const float* w22 = (const float*)d_in[7];
  const float* b22 = (const float*)d_in[8];
  const float* w23 = (const float*)d_in[9];
  const float* b23 = (const float*)d_in[10];
  const float* n2w = (const float*)d_in[11];
  const float* n2b = (const float*)d_in[12];
  const float* w3  = (const float*)d_in[13];
  const float* b3  = (const float*)d_in[14];

  char* ws = (char*)d_ws;
  size_t off = 0;
  unsigned short* wb = (unsigned short*)(ws + off); off += (size_t)4 * NCH * NCH * 2;
  off = (off + 255) & ~(size_t)255;
  unsigned short* w3e = (unsigned short*)(ws + off); off += (size_t)NB * NCH * NCH * 2;
  off = (off + 255) & ~(size_t)255;
  float* b3e = (float*)(ws + off); off += NB * NCH * 4;
  float* AC1 = (float*)(ws + off); off += NB * 2 * NCH * 4;
  float* AC2 = (float*)(ws + off); off += NB * 2 * NCH * 4;
  unsigned short* ACbf1 = (unsigned short*)(ws + off); off += NB * 2 * NCH * 2;
  unsigned short* ACbf2 = (unsigned short*)(ws + off); off += NB * 2 * NCH * 2;
  off = (off + 255) & ~(size_t)255;
  float* part1 = (float*)(ws + off); off += (size_t)NBLK * 2 * 4;
  float* part2 = (float*)(ws + off); off += (size_t)NBLK * 2 * 4;
  off = (off + 255) & ~(size_t)255;
  unsigned short* R1 = (unsigned short*)(ws + off);   // 100.7 MB bf16 (ws)
  unsigned short* R2 = (unsigned short*)d_out;        // bf16 scratch in d_out

  prep_weights<<<(4 * NCH * NCH + 255) / 256, 256, 0, stream>>>(w1, w21, w22, w23, wb);

  // K1: x -> R1 (conv w1 + b1), stats1
  pass1<<<NBLK, 256, 0, stream>>>(x, wb + 0 * NCH * NCH, b1, R1, part1);
  stats_finalize<<<NB, 256, 0, stream>>>(part1, n1w, n1b, AC1, ACbf1);

  // K2a: norm1+gelu fused staging, H-shift, conv w22 + b22: R1 -> R2
  pass2a<<<NBLK, 256, 0, stream>>>(R1, wb + 1 * NCH * NCH, b22, R2, ACbf1);

  // K2bc: D-shift stage -> w21 -> T -> W-shift -> w23 + gelu + stats2: R2 -> R1
  pass2bc<<<NBLK, 256, 0, stream>>>(R2, wb + 2 * NCH * NCH, b21,
                                    wb + 3 * NCH * NCH, b23, R1, part2);
  stats_finalize<<<NB, 256, 0, stream>>>(part2, n2w, n2b, AC2, ACbf2);
  prep_w3<<<NB, NCH, 0, stream>>>(w3, b3, AC2, w3e, b3e);

  // K3: folded norm2 + conv w3: R1 -> d_out (f32 channel-major)
  pass3<<<NBLK, 256, 0, stream>>>(R1, w3e, b3e, (float*)d_out);
}